// Round 12
// baseline (182.263 us; speedup 1.0000x reference)
//
#include <hip/hip_runtime.h>
#include <math.h>

typedef __attribute__((ext_vector_type(4)))  short short4v;
typedef __attribute__((ext_vector_type(8)))  short short8v;
typedef __attribute__((ext_vector_type(4)))  float f32x4;

// ---------------- ws layout (float units) ----------------
// accum[0..255]: [0]=loss, [1..127]=sum p*inner, [128..254]=sum inner
// logQT [100][256] ; Q [256][100]
// wpk (ushort) [256 nodes][64 kblk][64]: per 32-K block, 8 chunks of 8 shorts =
//   [hi c0..c3 | lo c0..c3], chunk index XOR-swizzled by (node&7). Row 255 = 0.
// part[z] [8192][256] fp32, z < ksplit
#define OFF_LOGQT 256
#define OFF_Q     25856
#define OFF_WPK   51456
#define OFF_PART  575744
#define PART_STRIDE 2097152         // 8192*256 floats

__device__ __forceinline__ unsigned short f2bf(float f) {   // RNE to bf16 bits
    unsigned int b = __float_as_uint(f);
    unsigned int r = (b + 0x7FFFu + ((b >> 16) & 1u)) >> 16;
    return (unsigned short)r;
}
__device__ __forceinline__ float bf2f(unsigned short u) {
    return __uint_as_float(((unsigned int)u) << 16);
}
__device__ __forceinline__ void gl16(const void* g, void* l) {
    __builtin_amdgcn_global_load_lds(
        (const __attribute__((address_space(1))) unsigned int*)g,
        (__attribute__((address_space(3))) unsigned int*)l, 16, 0, 0);
}

// ---------------- kernel: prep = W->packed-swizzled hi/lo + log_softmax + zero ----------------
__global__ __launch_bounds__(256) void k_prep(const float* __restrict__ W,
                                              unsigned short* __restrict__ wpk,
                                              const float* __restrict__ lp,
                                              float* __restrict__ logQT,
                                              float* __restrict__ Q,
                                              float* __restrict__ accum)
{
    const int bx = blockIdx.x, tid = threadIdx.x;
    if (bx < 256) {
        if (bx == 0) accum[tid] = 0.f;
        int g = (bx * 256 + tid) * 8;            // 8 consecutive k of one node
        int n = g >> 11;
        int c = g & 2047;                        // c % 8 == 0
        unsigned short h[8], l[8];
        if (n < 255) {
            const float* src = W + (size_t)n * 2048 + c;
            float4 v0 = *(const float4*)src;
            float4 v1 = *(const float4*)(src + 4);
            float vv[8] = {v0.x, v0.y, v0.z, v0.w, v1.x, v1.y, v1.z, v1.w};
#pragma unroll
            for (int j = 0; j < 8; ++j) {
                h[j] = f2bf(vv[j]);
                l[j] = f2bf(vv[j] - bf2f(h[j]));
            }
        } else {
#pragma unroll
            for (int j = 0; j < 8; ++j) { h[j] = 0; l[j] = 0; }
        }
        size_t db = (size_t)n * 4096 + (size_t)(c >> 5) * 64;
        int lc = (c >> 3) & 3;                   // logical chunk within kblk
        int sw = n & 7;
        unsigned short* hd = wpk + db + (size_t)((lc ^ sw) << 3);
        unsigned short* ld = wpk + db + (size_t)(((4 + lc) ^ sw) << 3);
#pragma unroll
        for (int j = 0; j < 8; ++j) { hd[j] = h[j]; ld[j] = l[j]; }
    } else {
        int w = tid >> 6, lane = tid & 63;
        int r = (bx - 256) * 4 + w;
        float v0 = (lane < 100)      ? lp[r * 100 + lane]      : -INFINITY;
        float v1 = (lane + 64 < 100) ? lp[r * 100 + lane + 64] : -INFINITY;
        float m = fmaxf(v0, v1);
        for (int s = 32; s; s >>= 1) m = fmaxf(m, __shfl_xor(m, s));
        float e = 0.f;
        if (lane < 100)      e += expf(v0 - m);
        if (lane + 64 < 100) e += expf(v1 - m);
        for (int s = 32; s; s >>= 1) e += __shfl_xor(e, s);
        float logZ = m + logf(e);
        if (lane < 100) {
            float lq = v0 - logZ;
            Q[r * 100 + lane] = expf(lq);
            logQT[lane * 256 + r] = lq;
        }
        if (lane + 64 < 100) {
            float lq = v1 - logZ;
            Q[r * 100 + lane + 64] = expf(lq);
            logQT[(lane + 64) * 256 + r] = lq;
        }
    }
}

// ---------------- kernel: split-bf16 MFMA GEMM, double-buffered 2-phase ----------------
// BM=128, BN=128, BK=32; 4 waves (2x2 of 64x64); LDS 2 x (At 16K + Bt 16K) = 64 KB
// -> 2 blocks/CU. B staged via gl16 from pre-swizzled wpk; A converted in-kernel.
// grid (64, 2, ksplit=4); ksteps = 16.
__global__ __launch_bounds__(256, 2) void k_gemm4(const float* __restrict__ x,
                                                  const unsigned short* __restrict__ wpk,
                                                  float* __restrict__ part,
                                                  int ksteps)
{
    __shared__ __align__(16) unsigned short At[2][128 * 64];
    __shared__ __align__(16) unsigned short Bt[2][128 * 64];

    const int tid = threadIdx.x;
    const int w = tid >> 6, lane = tid & 63;
    const int wm = w >> 1, wn = w & 1;
    const int r16 = lane & 15, hb = lane >> 4;
    const int row0 = blockIdx.x * 128;
    const int col0 = blockIdx.y * 128;
    const int kz = blockIdx.z;
    const int kblk0 = kz * ksteps;
    float* pdst = part + (size_t)kz * PART_STRIDE;

    const int ar_ = tid >> 1, ahalf = tid & 1;   // A staging: row, 16-col half

    f32x4 acc[4][4] = {};

    auto GLA = [&](int s, float4* a) {
        const float* src = x + (size_t)(row0 + ar_) * 2048 + (kblk0 + s) * 32 + ahalf * 16;
#pragma unroll
        for (int it = 0; it < 4; ++it) a[it] = ((const float4*)src)[it];
    };
    auto GLB = [&](int s, int bi) {
        const int kblk = kblk0 + s;
#pragma unroll
        for (int it = 0; it < 4; ++it) {
            int ch = it * 256 + tid;
            int r = ch >> 3, c = ch & 7;
            gl16(wpk + (size_t)(col0 + r) * 4096 + kblk * 64 + c * 8, &Bt[bi][ch * 8]);
        }
    };
    auto CONVA = [&](const float4* a, int bi) {
        float vv[16];
#pragma unroll
        for (int it = 0; it < 4; ++it) {
            vv[it * 4 + 0] = a[it].x; vv[it * 4 + 1] = a[it].y;
            vv[it * 4 + 2] = a[it].z; vv[it * 4 + 3] = a[it].w;
        }
        unsigned short h[16], l[16];
#pragma unroll
        for (int j = 0; j < 16; ++j) {
            h[j] = f2bf(vv[j]);
            l[j] = f2bf(vv[j] - bf2f(h[j]));
        }
        const int base = ar_ * 64, sw = ar_ & 7;
#pragma unroll
        for (int q = 0; q < 2; ++q) {            // two hi chunks, two lo chunks
            int lcH = ahalf * 2 + q;
            short8v hv, lv;
#pragma unroll
            for (int j = 0; j < 8; ++j) { hv[j] = (short)h[q * 8 + j]; lv[j] = (short)l[q * 8 + j]; }
            *(short8v*)&At[bi][base + ((lcH ^ sw) << 3)]       = hv;
            *(short8v*)&At[bi][base + (((4 + lcH) ^ sw) << 3)] = lv;
        }
    };
    auto COMPUTE = [&](int bi) {
        short8v ah[4], al[4];
#pragma unroll
        for (int fm = 0; fm < 4; ++fm) {
            int ar = wm * 64 + fm * 16 + r16;
            int ab = ar * 64, sw = ar & 7;
            ah[fm] = *(const short8v*)&At[bi][ab + ((hb ^ sw) << 3)];
            al[fm] = *(const short8v*)&At[bi][ab + (((4 + hb) ^ sw) << 3)];
        }
#pragma unroll
        for (int fn = 0; fn < 4; ++fn) {
            int br = wn * 64 + fn * 16 + r16;
            int bb = br * 64, sw = br & 7;
            short8v bhh = *(const short8v*)&Bt[bi][bb + ((hb ^ sw) << 3)];
            short8v bll = *(const short8v*)&Bt[bi][bb + (((4 + hb) ^ sw) << 3)];
#pragma unroll
            for (int fm = 0; fm < 4; ++fm) {
                acc[fm][fn] = __builtin_amdgcn_mfma_f32_16x16x32_bf16(ah[fm], bhh, acc[fm][fn], 0, 0, 0);
                acc[fm][fn] = __builtin_amdgcn_mfma_f32_16x16x32_bf16(ah[fm], bll, acc[fm][fn], 0, 0, 0);
                acc[fm][fn] = __builtin_amdgcn_mfma_f32_16x16x32_bf16(al[fm], bhh, acc[fm][fn], 0, 0, 0);
            }
        }
    };

    // prologue
    float4 a0[4];
    GLA(0, a0);
    GLB(0, 0);
    CONVA(a0, 0);
    __syncthreads();

    int buf = 0;
    for (int s = 0; s < ksteps; ++s) {
        float4 aN[4];
        const bool pre = (s + 1 < ksteps);
        if (pre) { GLA(s + 1, aN); GLB(s + 1, buf ^ 1); }   // issue loads FIRST
        COMPUTE(buf);                                       // hides the loads
        if (pre) CONVA(aN, buf ^ 1);                        // after MFMA
        __syncthreads();                                    // drains vmcnt+lgkm
        buf ^= 1;
    }

#pragma unroll
    for (int fm = 0; fm < 4; ++fm)
#pragma unroll
        for (int fn = 0; fn < 4; ++fn) {
            int col = col0 + wn * 64 + fn * 16 + r16;
#pragma unroll
            for (int j = 0; j < 4; ++j) {
                int row = row0 + wm * 64 + fm * 16 + hb * 4 + j;
                pdst[(size_t)row * 256 + col] = acc[fm][fn][j];
            }
        }
}

// ---------------- kernel: fused sigmoid + tree pass ----------------
// 1024 blocks x 256 thr; 4 waves/block, 2 rows/wave, wave-local sync; reg accumulators.
__global__ __launch_bounds__(256) void k_tree(const float* __restrict__ part, int npart,
                                              const float* __restrict__ bias,
                                              const float* __restrict__ beta,
                                              const int* __restrict__ labels,
                                              const float* __restrict__ logQT,
                                              const float* __restrict__ Q,
                                              float* __restrict__ accum,
                                              float* __restrict__ out)
{
    __shared__ float psh[4][256];
    __shared__ float redPI[4][128];
    __shared__ float redI[4][128];
    __shared__ float lossw[4];
    const int tid = threadIdx.x;
    const int w = tid >> 6, lane = tid & 63;
    const int c0 = lane * 4;

    float4 bi, be;
    if (lane < 63) {
        bi = *(const float4*)&bias[c0];
        be = *(const float4*)&beta[c0];
    } else {
        bi = make_float4(bias[252], bias[253], bias[254], 0.f);
        be = make_float4(beta[252], beta[253], beta[254], 0.f);
    }

    float aPI0 = 0.f, aPI1 = 0.f, aI0 = 0.f, aI1 = 0.f, lossAcc = 0.f;

    for (int rr = 0; rr < 2; ++rr) {
        int b = blockIdx.x * 8 + w * 2 + rr;

        float4 s = make_float4(0.f, 0.f, 0.f, 0.f);
        for (int z = 0; z < npart; ++z) {
            float4 v = *(const float4*)&part[(size_t)z * PART_STRIDE + (size_t)b * 256 + c0];
            s.x += v.x; s.y += v.y; s.z += v.z; s.w += v.w;
        }
        float4 pv;
        pv.x = 1.f / (1.f + expf(-be.x * (s.x + bi.x)));
        pv.y = 1.f / (1.f + expf(-be.y * (s.y + bi.y)));
        pv.z = 1.f / (1.f + expf(-be.z * (s.z + bi.z)));
        pv.w = 1.f / (1.f + expf(-be.w * (s.w + bi.w)));
        *(float4*)&psh[w][c0] = pv;
        asm volatile("s_waitcnt lgkmcnt(0)" ::: "memory");
        __builtin_amdgcn_sched_barrier(0);

        int label = labels[b];
        float4 tq = *(const float4*)&logQT[(size_t)label * 256 + c0];

        float prefix = 1.f;
#pragma unroll
        for (int d = 0; d < 6; ++d) {
            int node = (1 << d) - 1 + (lane >> (6 - d));
            float g = psh[w][node];
            prefix *= ((lane >> (5 - d)) & 1) ? g : (1.f - g);
        }
        float g6  = psh[w][63 + lane];
        float p60 = prefix * (1.f - g6), p61 = prefix * g6;
        float g7a = psh[w][127 + 2 * lane];
        float g7b = psh[w][128 + 2 * lane];
        float f0 = p60 * (1.f - g7a), f1 = p60 * g7a;
        float f2 = p61 * (1.f - g7b), f3 = p61 * g7b;

        float lsum = f0 * tq.x + f1 * tq.y + f2 * tq.z + f3 * tq.w;

        float best = f0; int bestIdx = c0;
        if (f1 > best) { best = f1; bestIdx = c0 + 1; }
        if (f2 > best) { best = f2; bestIdx = c0 + 2; }
        if (f3 > best) { best = f3; bestIdx = c0 + 3; }

        for (int sft = 32; sft; sft >>= 1) lsum += __shfl_xor(lsum, sft);
        for (int sft = 32; sft; sft >>= 1) {
            float ov = __shfl_xor(best, sft);
            int   oi = __shfl_xor(bestIdx, sft);
            if (ov > best || (ov == best && oi < bestIdx)) { best = ov; bestIdx = oi; }
        }
        lossAcc += lsum;

        {
            int n = lane;
            float f = 1.f;
            int cur = n;
            while (cur > 0) {
                int par = (cur - 1) >> 1;
                float g = psh[w][par];
                f *= (cur == 2 * par + 2) ? g : (1.f - g);
                cur = par;
            }
            aPI0 += psh[w][n] * f;
            aI0  += f;
        }
        if (lane < 63) {
            int n = lane + 64;
            float f = 1.f;
            int cur = n;
            while (cur > 0) {
                int par = (cur - 1) >> 1;
                float g = psh[w][par];
                f *= (cur == 2 * par + 2) ? g : (1.f - g);
                cur = par;
            }
            aPI1 += psh[w][n] * f;
            aI1  += f;
        }

        const float* qrow = Q + (size_t)bestIdx * 100;
        float* orow = out + 1 + (size_t)b * 100;
        orow[lane] = qrow[lane];
        if (lane < 36) orow[64 + lane] = qrow[64 + lane];
    }

    redPI[w][lane] = aPI0;           redI[w][lane] = aI0;
    redPI[w][64 + lane] = (lane < 63) ? aPI1 : 0.f;
    redI [w][64 + lane] = (lane < 63) ? aI1  : 0.f;
    if (lane == 0) lossw[w] = lossAcc;
    __syncthreads();
    if (tid < 127) {
        float sPI = redPI[0][tid] + redPI[1][tid] + redPI[2][tid] + redPI[3][tid];
        float sI  = redI [0][tid] + redI [1][tid] + redI [2][tid] + redI [3][tid];
        atomicAdd(&accum[1 + tid],   sPI);
        atomicAdd(&accum[128 + tid], sI);
    }
    if (tid == 128) {
        atomicAdd(&accum[0], lossw[0] + lossw[1] + lossw[2] + lossw[3]);
    }
}

// ---------------- kernel: finalize scalars ----------------
__global__ __launch_bounds__(128) void k_final(const float* __restrict__ accum,
                                               float* __restrict__ out)
{
    __shared__ float s[128];
    int t = threadIdx.x;
    float term = 0.f;
    if (t < 127) {
        float a = accum[1 + t] / accum[128 + t];
        int depth = 32 - __clz(t + 1);
        float lmbda = 0.1f * exp2f(-(float)depth);
        term = -lmbda * 0.5f * (logf(a) + log1pf(-a));
    }
    s[t] = term;
    __syncthreads();
    if (t == 0) {
        float c = 0.f;
        for (int i = 0; i < 127; ++i) c += s[i];
        out[819201] = c;
        out[0] = -accum[0] / 8192.0f;
    }
}

// ---------------- launcher ----------------
extern "C" void kernel_launch(void* const* d_in, const int* in_sizes, int n_in,
                              void* d_out, int out_size, void* d_ws, size_t ws_size,
                              hipStream_t stream)
{
    const float* x      = (const float*)d_in[0];
    const int*   labels = (const int*)  d_in[1];
    const float* W      = (const float*)d_in[2];
    const float* bias   = (const float*)d_in[3];
    const float* beta   = (const float*)d_in[4];
    const float* leaf   = (const float*)d_in[5];
    float* out = (float*)d_out;
    float* ws  = (float*)d_ws;

    float*          accum = ws;
    float*          logQT = ws + OFF_LOGQT;
    float*          Q     = ws + OFF_Q;
    unsigned short* wpk   = (unsigned short*)(ws + OFF_WPK);
    float*          part  = ws + OFF_PART;

    auto need = [](int k) { return (size_t)(OFF_PART + (size_t)k * PART_STRIDE) * sizeof(float); };
    int ksplit = (ws_size >= need(4)) ? 4 : (ws_size >= need(2)) ? 2 : 1;
    int ksteps = 64 / ksplit;          // K-blocks of 32: 2048/32 = 64 total

    k_prep<<<320, 256, 0, stream>>>(W, wpk, leaf, logQT, Q, accum);
    k_gemm4<<<dim3(64, 2, ksplit), 256, 0, stream>>>(x, wpk, part, ksteps);
    k_tree<<<1024, 256, 0, stream>>>(part, ksplit, bias, beta, labels, logQT, Q, accum, out);
    k_final<<<1, 128, 0, stream>>>(accum, out);
}